// Round 1
// baseline (16424.763 us; speedup 1.0000x reference)
//
#include <hip/hip_runtime.h>

// GeoMapNet fused forward: 8-layer transformer encoder, B=65536, S=3, D=100.
// One block = 256 threads = NB(8) batch elements, fully resident in LDS.
// fp32 VALU everywhere (CDNA4 has no fp32 MFMA) -- correctness baseline.

namespace {
constexpr int S   = 3;
constexpr int DIN = 72;
constexpr int D   = 100;
constexpr int H   = 10;
constexpr int DH  = 10;
constexpr int FF  = 512;
constexpr int L   = 8;
constexpr int CLS = 40;
constexpr int SD  = S * D;      // 300
constexpr int NB  = 8;          // batch elements per block
constexpr int NT  = 256;        // threads per block
constexpr int FCH = 256;        // FFN hidden chunk (FF/FCH = 2 chunks)
constexpr float SCALE = 0.3162277660168379f;  // DH^-0.5
}

// LayerNorm over each (e,s) row of 100: 8 lanes per row, 24 rows = 192 threads.
// dst may alias srcB (values cached in registers before any write).
__device__ __forceinline__ void layernorm_rows(float* dst, const float* srcA,
                                               const float* srcB,
                                               const float* __restrict__ gamma,
                                               const float* __restrict__ beta,
                                               int tid) {
  if (tid < NB * S * 8) {
    const int row  = tid >> 3;   // 0..23  (= e*S + s)
    const int lane = tid & 7;
    const float* pa = srcA + row * D;
    const float* pb = srcB ? srcB + row * D : nullptr;
    float vals[13];
    float sum = 0.f;
    int cnt = 0;
    for (int f = lane; f < D; f += 8) {
      float v = pa[f];
      if (pb) v += pb[f];
      vals[cnt++] = v;
      sum += v;
    }
#pragma unroll
    for (int o = 4; o; o >>= 1) sum += __shfl_xor(sum, o, 8);
    const float mean = sum * (1.f / D);
    float var = 0.f;
    for (int i = 0; i < cnt; ++i) {
      const float dd = vals[i] - mean;
      var += dd * dd;
    }
#pragma unroll
    for (int o = 4; o; o >>= 1) var += __shfl_xor(var, o, 8);
    const float rstd = rsqrtf(var * (1.f / D) + 1e-5f);
    float* pd = dst + row * D;
    cnt = 0;
    for (int f = lane; f < D; f += 8) {
      pd[f] = (vals[cnt++] - mean) * rstd * gamma[f] + beta[f];
    }
  }
}

__global__ __launch_bounds__(NT, 2)
void geomap_fwd(const float* __restrict__ gx,
                const float* __restrict__ We, const float* __restrict__ be,
                const float* __restrict__ pe,
                const float* __restrict__ Wq, const float* __restrict__ bq,
                const float* __restrict__ Wk, const float* __restrict__ bk,
                const float* __restrict__ Wv, const float* __restrict__ bv,
                const float* __restrict__ Wo, const float* __restrict__ bo,
                const float* __restrict__ g1, const float* __restrict__ bt1,
                const float* __restrict__ W1, const float* __restrict__ b1,
                const float* __restrict__ W2, const float* __restrict__ b2,
                const float* __restrict__ g2, const float* __restrict__ bt2,
                const float* __restrict__ Wf, const float* __restrict__ bfc,
                float* __restrict__ gout) {
  // Activations, flat [es][100] rows where es = e*S + s (so [e][s*100+d]).
  __shared__ float sX[NB * SD];  // current activation
  __shared__ float sQ[NB * SD];  // Q, then attention context
  __shared__ float sK[NB * SD];  // K, then Wo-out (pre-LN1)
  __shared__ float sV[NB * SD];  // V, then FFN output accumulator
  __shared__ float sH[NB * S * FCH];  // x staging (1728 f32) / FFN hidden chunk

  const int tid = threadIdx.x;
  const long long blk = blockIdx.x;

  // ---- stage x [NB][S][DIN] (contiguous, coalesced float4) ----
  {
    const float4* src = reinterpret_cast<const float4*>(gx + blk * (NB * S * DIN));
    float4* dst = reinterpret_cast<float4*>(sH);
    for (int i = tid; i < NB * S * DIN / 4; i += NT) dst[i] = src[i];
  }
  __syncthreads();

  // ---- embedding: sX[es*100+d] = x[e][s] . We[d] + be[d] + pe[s*100+d] ----
  for (int job = tid; job < S * D; job += NT) {
    const int s = job / D, d = job % D;
    const float4* wr = reinterpret_cast<const float4*>(We + d * DIN);
    const float bias = be[d] + pe[s * D + d];
    float acc[NB];
#pragma unroll
    for (int e = 0; e < NB; ++e) acc[e] = bias;
    for (int kq = 0; kq < DIN / 4; ++kq) {
      const float4 w4 = wr[kq];
#pragma unroll
      for (int e = 0; e < NB; ++e) {
        const float4 x4 =
            *reinterpret_cast<const float4*>(sH + (e * S + s) * DIN + kq * 4);
        acc[e] += w4.x * x4.x + w4.y * x4.y + w4.z * x4.z + w4.w * x4.w;
      }
    }
#pragma unroll
    for (int e = 0; e < NB; ++e) sX[(e * S + s) * D + d] = acc[e];
  }
  __syncthreads();

  for (int li = 0; li < L; ++li) {
    const float* Wq_l = Wq + li * D * D;
    const float* Wk_l = Wk + li * D * D;
    const float* Wv_l = Wv + li * D * D;
    const float* Wo_l = Wo + li * D * D;
    const float* W1_l = W1 + li * FF * D;
    const float* W2_l = W2 + li * D * FF;

    // ---- QKV projections: 900 jobs = (s, which, f), acc over 8 elements ----
    for (int job = tid; job < S * 3 * D; job += NT) {
      const int s = job / (3 * D);
      const int r = job % (3 * D);
      const int which = r / D;
      const int f = r % D;
      const float* wbase =
          (which == 0 ? Wq_l : which == 1 ? Wk_l : Wv_l) + f * D;
      const float bias =
          (which == 0 ? bq : which == 1 ? bk : bv)[li * D + f];
      const float4* wr = reinterpret_cast<const float4*>(wbase);
      float* dst = (which == 0 ? sQ : which == 1 ? sK : sV);
      float acc[NB];
#pragma unroll
      for (int e = 0; e < NB; ++e) acc[e] = bias;
      for (int kq = 0; kq < D / 4; ++kq) {
        const float4 w4 = wr[kq];
#pragma unroll
        for (int e = 0; e < NB; ++e) {
          const float4 x4 =
              *reinterpret_cast<const float4*>(sX + (e * S + s) * D + kq * 4);
          acc[e] += w4.x * x4.x + w4.y * x4.y + w4.z * x4.z + w4.w * x4.w;
        }
      }
#pragma unroll
      for (int e = 0; e < NB; ++e) dst[(e * S + s) * D + f] = acc[e];
    }
    __syncthreads();

    // ---- attention: faithful .view head split -- head h covers flat
    // offsets h*30 + s'*10 + j of each element's 300-vector ----
    if (tid < NB * H * S) {
      const int e = tid / (H * S);
      const int r = tid % (H * S);
      const int h = r / S, sq = r % S;
      const float* Qp = sQ + e * SD + h * 30 + sq * DH;
      float sc[S];
#pragma unroll
      for (int t = 0; t < S; ++t) {
        const float* Kp = sK + e * SD + h * 30 + t * DH;
        float sum = 0.f;
#pragma unroll
        for (int j = 0; j < DH; ++j) sum += Qp[j] * Kp[j];
        sc[t] = sum * SCALE;
      }
      const float m = fmaxf(sc[0], fmaxf(sc[1], sc[2]));
      float p0 = __expf(sc[0] - m), p1 = __expf(sc[1] - m),
            p2 = __expf(sc[2] - m);
      const float inv = 1.f / (p0 + p1 + p2);
      p0 *= inv; p1 *= inv; p2 *= inv;
      const float* Vp = sV + e * SD + h * 30;
      float ctx[DH];
#pragma unroll
      for (int j = 0; j < DH; ++j)
        ctx[j] = p0 * Vp[j] + p1 * Vp[DH + j] + p2 * Vp[2 * DH + j];
      float* Op = sQ + e * SD + h * 30 + sq * DH;  // overwrite own Q row only
#pragma unroll
      for (int j = 0; j < DH; ++j) Op[j] = ctx[j];
    }
    __syncthreads();

    // ---- Wo projection + residual -> sK ----
    for (int job = tid; job < S * D; job += NT) {
      const int s = job / D, f = job % D;
      const float4* wr = reinterpret_cast<const float4*>(Wo_l + f * D);
      const float bias = bo[li * D + f];
      float acc[NB];
#pragma unroll
      for (int e = 0; e < NB; ++e) acc[e] = bias;
      for (int kq = 0; kq < D / 4; ++kq) {
        const float4 w4 = wr[kq];
#pragma unroll
        for (int e = 0; e < NB; ++e) {
          const float4 x4 =
              *reinterpret_cast<const float4*>(sQ + (e * S + s) * D + kq * 4);
          acc[e] += w4.x * x4.x + w4.y * x4.y + w4.z * x4.z + w4.w * x4.w;
        }
      }
#pragma unroll
      for (int e = 0; e < NB; ++e) {
        const int idx = (e * S + s) * D + f;
        sK[idx] = acc[e] + sX[idx];
      }
    }
    __syncthreads();

    // ---- LN1: sX = LN(sK); also init FFN accumulator sV = b2 ----
    layernorm_rows(sX, sK, nullptr, g1 + li * D, bt1 + li * D, tid);
    for (int idx = tid; idx < NB * SD; idx += NT)
      sV[idx] = b2[li * D + (idx % D)];
    __syncthreads();

    // ---- FFN in chunks of FCH hidden units ----
    for (int fc = 0; fc < FF; fc += FCH) {
      // hidden: sH[es*FCH+fj] = relu(sX[es] . W1[fc+fj] + b1), 256 jobs exact
      for (int fj = tid; fj < FCH; fj += NT) {
        const float4* wr =
            reinterpret_cast<const float4*>(W1_l + (fc + fj) * D);
        const float bias = b1[li * FF + fc + fj];
        float acc[NB * S];
#pragma unroll
        for (int rr = 0; rr < NB * S; ++rr) acc[rr] = bias;
        for (int kq = 0; kq < D / 4; ++kq) {
          const float4 w4 = wr[kq];
#pragma unroll
          for (int rr = 0; rr < NB * S; ++rr) {
            const float4 x4 =
                *reinterpret_cast<const float4*>(sX + rr * D + kq * 4);
            acc[rr] += w4.x * x4.x + w4.y * x4.y + w4.z * x4.z + w4.w * x4.w;
          }
        }
#pragma unroll
        for (int rr = 0; rr < NB * S; ++rr)
          sH[rr * FCH + fj] = fmaxf(acc[rr], 0.f);
      }
      __syncthreads();
      // accumulate: sV[es*100+d] += sH[es] . W2[d][fc:fc+FCH]
      for (int job = tid; job < S * D; job += NT) {
        const int s = job / D, d = job % D;
        const float4* wr =
            reinterpret_cast<const float4*>(W2_l + d * FF + fc);
        float acc[NB];
#pragma unroll
        for (int e = 0; e < NB; ++e) acc[e] = 0.f;
        for (int kq = 0; kq < FCH / 4; ++kq) {
          const float4 w4 = wr[kq];
#pragma unroll
          for (int e = 0; e < NB; ++e) {
            const float4 h4 = *reinterpret_cast<const float4*>(
                sH + (e * S + s) * FCH + kq * 4);
            acc[e] += w4.x * h4.x + w4.y * h4.y + w4.z * h4.z + w4.w * h4.w;
          }
        }
#pragma unroll
        for (int e = 0; e < NB; ++e) sV[(e * S + s) * D + d] += acc[e];
      }
      __syncthreads();
    }

    // ---- LN2: sX = LN(sV + sX)  (in-place safe: values cached per lane) ----
    layernorm_rows(sX, sV, sX, g2 + li * D, bt2 + li * D, tid);
    __syncthreads();
  }

  // ---- classifier: out[e][c] = sX[e][:300] . Wf[c] + bf[c] ----
  for (int job = tid; job < NB * CLS; job += NT) {
    const int e = job / CLS, c = job % CLS;
    const float4* wr = reinterpret_cast<const float4*>(Wf + c * SD);
    const float* xr = sX + e * SD;
    float acc = bfc[c];
    for (int kq = 0; kq < SD / 4; ++kq) {
      const float4 w4 = wr[kq];
      const float4 x4 = *reinterpret_cast<const float4*>(xr + kq * 4);
      acc += w4.x * x4.x + w4.y * x4.y + w4.z * x4.z + w4.w * x4.w;
    }
    gout[(blk * NB + e) * CLS + c] = acc;
  }
}

extern "C" void kernel_launch(void* const* d_in, const int* in_sizes, int n_in,
                              void* d_out, int out_size, void* d_ws,
                              size_t ws_size, hipStream_t stream) {
  const float* x   = (const float*)d_in[0];
  // d_in[1] label, d_in[2] fa_label: unused by the forward pass
  const float* We  = (const float*)d_in[3];
  const float* be  = (const float*)d_in[4];
  const float* pe  = (const float*)d_in[5];
  const float* Wq  = (const float*)d_in[6];
  const float* bq  = (const float*)d_in[7];
  const float* Wk  = (const float*)d_in[8];
  const float* bk  = (const float*)d_in[9];
  const float* Wv  = (const float*)d_in[10];
  const float* bv  = (const float*)d_in[11];
  const float* Wo  = (const float*)d_in[12];
  const float* bo  = (const float*)d_in[13];
  const float* g1  = (const float*)d_in[14];
  const float* bt1 = (const float*)d_in[15];
  const float* W1  = (const float*)d_in[16];
  const float* b1  = (const float*)d_in[17];
  const float* W2  = (const float*)d_in[18];
  const float* b2  = (const float*)d_in[19];
  const float* g2  = (const float*)d_in[20];
  const float* bt2 = (const float*)d_in[21];
  const float* Wf  = (const float*)d_in[22];
  const float* bf  = (const float*)d_in[23];
  float* out = (float*)d_out;

  const int B = in_sizes[0] / (S * DIN);
  const int blocks = B / NB;
  hipLaunchKernelGGL(geomap_fwd, dim3(blocks), dim3(NT), 0, stream,
                     x, We, be, pe, Wq, bq, Wk, bk, Wv, bv, Wo, bo,
                     g1, bt1, W1, b1, W2, b2, g2, bt2, Wf, bf, out);
}

// Round 2
// 1818.674 us; speedup vs baseline: 9.0312x; 9.0312x over previous
//
#include <hip/hip_runtime.h>

// GeoMapNet fused forward, MFMA bf16 edition.
// Block = 256 threads (4 waves) = NB(16) batch elements = 48 (e,s) rows.
// All GEMMs via v_mfma_f32_16x16x32_bf16 with W as the A operand (so C/D rows
// index output features n; each lane owns 4 consecutive n for one X-row ->
// vectorized epilogue). fp32 master activations + residual + LN in LDS.
// Weights pre-packed to bf16 fragment blocks in d_ws by prep_weights.

typedef __attribute__((ext_vector_type(8))) short short8;   // 8 bf16 (4 VGPR)
typedef __attribute__((ext_vector_type(4))) float floatx4;  // MFMA C/D

namespace {
constexpr int S = 3, DIN = 72, D = 100, Hh = 10, FF = 512, L = 8, CLS = 40;
constexpr int NB = 16, R = 48, NT = 256;
constexpr int LDA = 136;  // sA/sH row stride in bf16 (16B-aligned rows, 2-way-max banks)
constexpr int LDQ = 104;  // sQ/sK/sV row stride in bf16
constexpr float SCALE = 0.3162277660168379f;  // DH^-0.5

// d_ws layout (bf16 element offsets). Fragment block = 64 lanes x 8 bf16 = 1KB.
constexpr int PL_QKVO = 7 * 4 * 64 * 8;    // 14336 elems / layer (7 nt, 4 ks)
constexpr int WQ_OFF = 0;
constexpr int WK_OFF = WQ_OFF + L * PL_QKVO;
constexpr int WV_OFF = WK_OFF + L * PL_QKVO;
constexpr int WO_OFF = WV_OFF + L * PL_QKVO;
constexpr int PL_W1 = 32 * 4 * 64 * 8;     // 65536 elems / layer (32 nt, 4 ks)
constexpr int W1_OFF = WO_OFF + L * PL_QKVO;
constexpr int PL_W2 = 7 * 16 * 64 * 8;     // 57344 elems / layer (7 nt, 16 ks)
constexpr int W2_OFF = W1_OFF + L * PL_W1;
// total = 1,441,792 bf16 = 2,883,584 bytes of d_ws
}  // namespace

__device__ __forceinline__ unsigned short f2bf(float f) {  // RTNE
  unsigned int u = __float_as_uint(f);
  u = u + 0x7fffu + ((u >> 16) & 1u);
  return (unsigned short)(u >> 16);
}

__device__ __forceinline__ void load10(float* o, const unsigned short* p) {
  const unsigned int* u = (const unsigned int*)p;  // 4B-aligned (even col)
#pragma unroll
  for (int w = 0; w < 5; ++w) {
    unsigned int x = u[w];
    o[2 * w]     = __uint_as_float(x << 16);
    o[2 * w + 1] = __uint_as_float(x & 0xffff0000u);
  }
}

// ---------------- weight pre-pack: fp32 row-major -> bf16 fragment blocks ---
__global__ void prep_weights(const float* __restrict__ Wq, const float* __restrict__ Wk,
                             const float* __restrict__ Wv, const float* __restrict__ Wo,
                             const float* __restrict__ W1, const float* __restrict__ W2,
                             unsigned short* __restrict__ ws) {
  const int gid = blockIdx.x * 256 + threadIdx.x;
  constexpr int T_QKVO = 8 * 7 * 4 * 64;          // per tensor: 14336 threads
  constexpr int T_W1 = 8 * 32 * 4 * 64;           // 65536
  constexpr int T_W2 = 8 * 7 * 16 * 64;           // 57344
  if (gid >= 4 * T_QKVO + T_W1 + T_W2) return;

  const float* src;
  unsigned short* dst;
  int within, ntc, ksc, N, Ksrc, lstride;
  if (gid < 4 * T_QKVO) {
    const int t = gid / T_QKVO;
    within = gid % T_QKVO;
    src = (t == 0 ? Wq : t == 1 ? Wk : t == 2 ? Wv : Wo);
    dst = ws + (t == 0 ? WQ_OFF : t == 1 ? WK_OFF : t == 2 ? WV_OFF : WO_OFF);
    ntc = 7; ksc = 4; N = 100; Ksrc = 100; lstride = 10000;
  } else if (gid < 4 * T_QKVO + T_W1) {
    within = gid - 4 * T_QKVO;
    src = W1; dst = ws + W1_OFF;
    ntc = 32; ksc = 4; N = 512; Ksrc = 100; lstride = 51200;
  } else {
    within = gid - 4 * T_QKVO - T_W1;
    src = W2; dst = ws + W2_OFF;
    ntc = 7; ksc = 16; N = 100; Ksrc = 512; lstride = 51200;
  }
  const int lane = within & 63;
  int tmp = within >> 6;
  const int ks = tmp % ksc; tmp /= ksc;
  const int nt = tmp % ntc;
  const int lay = tmp / ntc;
  const int n = nt * 16 + (lane & 15);
  const int kb = ks * 32 + (lane >> 4) * 8;
  const float* sp = src + lay * lstride + n * Ksrc;
  unsigned short o[8];
#pragma unroll
  for (int j = 0; j < 8; ++j) {
    const int k = kb + j;
    float v = (n < N && k < Ksrc) ? sp[k] : 0.f;
    o[j] = f2bf(v);
  }
  uint4 pk = make_uint4((unsigned)o[0] | ((unsigned)o[1] << 16),
                        (unsigned)o[2] | ((unsigned)o[3] << 16),
                        (unsigned)o[4] | ((unsigned)o[5] << 16),
                        (unsigned)o[6] | ((unsigned)o[7] << 16));
  *reinterpret_cast<uint4*>(dst + (size_t)within * 8) = pk;
}

// LayerNorm over 48 rows of 100; 4 lanes/row (192 threads), fully vectorized.
// Writes fp32 master (dst) AND bf16 A-buffer (sAbf). srcRes may alias dst.
__device__ __forceinline__ void ln_rows(float* dst, const float* srcA,
                                        const float* srcRes,
                                        const float* __restrict__ g,
                                        const float* __restrict__ b,
                                        unsigned short* sAbf, int tid) {
  if (tid < 192) {
    const int row = tid >> 2, ln = tid & 3;
    const int cnt = (ln == 0) ? 7 : 6;  // cols: i*16 + ln*4 (< 100)
    floatx4 v[7];
    float sum = 0.f;
    for (int i = 0; i < cnt; ++i) {
      const int col = i * 16 + ln * 4;
      floatx4 t = *(const floatx4*)(srcA + row * 100 + col);
      if (srcRes) t += *(const floatx4*)(srcRes + row * 100 + col);
      v[i] = t;
      sum += t.x + t.y + t.z + t.w;
    }
    sum += __shfl_xor(sum, 1, 4);
    sum += __shfl_xor(sum, 2, 4);
    const float mean = sum * 0.01f;
    float var = 0.f;
    for (int i = 0; i < cnt; ++i) {
      floatx4 d = v[i] - mean;
      var += d.x * d.x + d.y * d.y + d.z * d.z + d.w * d.w;
    }
    var += __shfl_xor(var, 1, 4);
    var += __shfl_xor(var, 2, 4);
    const float rstd = rsqrtf(var * 0.01f + 1e-5f);
    for (int i = 0; i < cnt; ++i) {
      const int col = i * 16 + ln * 4;
      const floatx4 gg = *(const floatx4*)(g + col);
      const floatx4 bb = *(const floatx4*)(b + col);
      floatx4 o = (v[i] - mean) * rstd * gg + bb;
      *(floatx4*)(dst + row * 100 + col) = o;
      unsigned int u0 = (unsigned)f2bf(o.x) | ((unsigned)f2bf(o.y) << 16);
      unsigned int u1 = (unsigned)f2bf(o.z) | ((unsigned)f2bf(o.w) << 16);
      *reinterpret_cast<uint2*>(sAbf + row * LDA + col) = make_uint2(u0, u1);
    }
  }
}

__global__ __launch_bounds__(NT, 2)
void geomap_mfma(const float* __restrict__ gx,
                 const float* __restrict__ We, const float* __restrict__ be,
                 const float* __restrict__ pe,
                 const float* __restrict__ bq, const float* __restrict__ bk,
                 const float* __restrict__ bv, const float* __restrict__ bo,
                 const float* __restrict__ g1, const float* __restrict__ bt1,
                 const float* __restrict__ b1, const float* __restrict__ b2,
                 const float* __restrict__ g2, const float* __restrict__ bt2,
                 const float* __restrict__ Wf, const float* __restrict__ bfc,
                 const unsigned short* __restrict__ ws,
                 float* __restrict__ gout) {
  // 81408 B total -> 2 blocks/CU (<= 81920)
  __shared__ __align__(16) char smem[81408];
  unsigned short* sA  = (unsigned short*)smem;            // [48][136] bf16 A-buf
  unsigned short* sQb = (unsigned short*)(smem + 13056);  // [48][104] bf16
  unsigned short* sKb = (unsigned short*)(smem + 23040);
  unsigned short* sVb = (unsigned short*)(smem + 33024);
  unsigned short* sH  = (unsigned short*)(smem + 23040);  // [48][136] aliases K,V
  float* sXf  = (float*)(smem + 43008);                   // [48][100] fp32 master
  float* sAcc = (float*)(smem + 62208);                   // [48][100] fp32 accum

  const int tid = threadIdx.x;
  const int lane = tid & 63;
  const int wid = tid >> 6;
  const int l15 = lane & 15;
  const int quad = lane >> 4;
  const int blk = blockIdx.x;

  // zero sA so K-pad cols [100,128) stay 0 forever
  for (int i = tid; i < R * LDA / 2; i += NT) ((unsigned int*)sA)[i] = 0u;
  {  // stage x [16][3][72] into sAcc
    const floatx4* src = (const floatx4*)(gx + (size_t)blk * (NB * S * DIN));
    floatx4* dst = (floatx4*)sAcc;
    for (int i = tid; i < NB * S * DIN / 4; i += NT) dst[i] = src[i];
  }
  __syncthreads();

  // ---- embedding (VALU, 0.3% of FLOPs): sXf/sA = x @ We^T + be + pe ----
  for (int job = tid; job < S * D; job += NT) {
    const int s = job / D, d = job % D;
    const floatx4* wr = (const floatx4*)(We + d * DIN);
    const float bias = be[d] + pe[s * D + d];
    float acc[NB];
#pragma unroll
    for (int e = 0; e < NB; ++e) acc[e] = bias;
    for (int kq = 0; kq < DIN / 4; ++kq) {
      const floatx4 w4 = wr[kq];
#pragma unroll
      for (int e = 0; e < NB; ++e) {
        const floatx4 x4 = *(const floatx4*)(sAcc + (e * S + s) * DIN + kq * 4);
        acc[e] += w4.x * x4.x + w4.y * x4.y + w4.z * x4.z + w4.w * x4.w;
      }
    }
#pragma unroll
    for (int e = 0; e < NB; ++e) {
      const int rr = e * S + s;
      sXf[rr * 100 + d] = acc[e];
      sA[rr * LDA + d] = f2bf(acc[e]);
    }
  }
  __syncthreads();

  for (int lay = 0; lay < L; ++lay) {
    // ---- QKV: D[n][xrow] = W[n][:] . X[xrow][:], X-frags held in regs ----
    {
      short8 xf[3][4];
#pragma unroll
      for (int mt = 0; mt < 3; ++mt)
#pragma unroll
        for (int ks = 0; ks < 4; ++ks)
          xf[mt][ks] = *(const short8*)(sA + (mt * 16 + l15) * LDA + ks * 32 + quad * 8);
      for (int u = wid; u < 21; u += 4) {
        const int mat = u / 7, nt = u % 7;
        const unsigned short* wb =
            ws + (mat == 0 ? WQ_OFF : mat == 1 ? WK_OFF : WV_OFF) +
            lay * PL_QKVO + ((size_t)(nt * 4) * 64 + lane) * 8;
        const float* bsrc = (mat == 0 ? bq : mat == 1 ? bk : bv) + lay * D;
        const int n0 = nt * 16 + quad * 4;
        floatx4 bias = {0.f, 0.f, 0.f, 0.f};
        if (n0 < D) bias = *(const floatx4*)(bsrc + n0);
        short8 wf[4];
#pragma unroll
        for (int ks = 0; ks < 4; ++ks) wf[ks] = *(const short8*)(wb + ks * 512);
        floatx4 a0 = bias, a1 = bias, a2 = bias;
#pragma unroll
        for (int ks = 0; ks < 4; ++ks) {
          a0 = __builtin_amdgcn_mfma_f32_16x16x32_bf16(wf[ks], xf[0][ks], a0, 0, 0, 0);
          a1 = __builtin_amdgcn_mfma_f32_16x16x32_bf16(wf[ks], xf[1][ks], a1, 0, 0, 0);
          a2 = __builtin_amdgcn_mfma_f32_16x16x32_bf16(wf[ks], xf[2][ks], a2, 0, 0, 0);
        }
        if (n0 < D) {
          unsigned short* dstb = (mat == 0 ? sQb : mat == 1 ? sKb : sVb);
          const floatx4 av[3] = {a0, a1, a2};
#pragma unroll
          for (int mt = 0; mt < 3; ++mt) {
            const int row = mt * 16 + l15;
            unsigned int u0 = (unsigned)f2bf(av[mt].x) | ((unsigned)f2bf(av[mt].y) << 16);
            unsigned int u1 = (unsigned)f2bf(av[mt].z) | ((unsigned)f2bf(av[mt].w) << 16);
            *reinterpret_cast<uint2*>(dstb + row * LDQ + n0) = make_uint2(u0, u1);
          }
        }
      }
    }
    __syncthreads();

    // ---- attention (VALU): faithful .view head split; ctx -> sA (bf16) ----
    for (int job = tid; job < NB * Hh * S; job += NT) {
      const int e = job / 30, r2 = job % 30, h = r2 / 3, sq = r2 % 3;
      const int p0 = h * 30 + sq * 10;
      const int rq = e * 3 + p0 / 100, cq = p0 % 100;
      float q[10];
      load10(q, sQb + rq * LDQ + cq);
      float sc[3];
#pragma unroll
      for (int t = 0; t < 3; ++t) {
        const int pk = h * 30 + t * 10;
        float kv[10];
        load10(kv, sKb + (e * 3 + pk / 100) * LDQ + (pk % 100));
        float s0 = 0.f;
#pragma unroll
        for (int j = 0; j < 10; ++j) s0 += q[j] * kv[j];
        sc[t] = s0 * SCALE;
      }
      const float m = fmaxf(sc[0], fmaxf(sc[1], sc[2]));
      float p0e = __expf(sc[0] - m), p1e = __expf(sc[1] - m), p2e = __expf(sc[2] - m);
      const float inv = 1.f / (p0e + p1e + p2e);
      p0e *= inv; p1e *= inv; p2e *= inv;
      float ctx[10];
#pragma unroll
      for (int j = 0; j < 10; ++j) ctx[j] = 0.f;
      const float pr[3] = {p0e, p1e, p2e};
#pragma unroll
      for (int t = 0; t < 3; ++t) {
        const int pv = h * 30 + t * 10;
        float vv[10];
        load10(vv, sVb + (e * 3 + pv / 100) * LDQ + (pv % 100));
#pragma unroll
        for (int j = 0; j < 10; ++j) ctx[j] += pr[t] * vv[j];
      }
      unsigned int* dp = (unsigned int*)(sA + rq * LDA + cq);
#pragma unroll
      for (int w = 0; w < 5; ++w)
        dp[w] = (unsigned)f2bf(ctx[2 * w]) | ((unsigned)f2bf(ctx[2 * w + 1]) << 16);
    }
    __syncthreads();

    // ---- Wo + residual -> sAcc (fp32) ----
    {
      short8 cf[3][4];
#pragma unroll
      for (int mt = 0; mt < 3; ++mt)
#pragma unroll
        for (int ks = 0; ks < 4; ++ks)
          cf[mt][ks] = *(const short8*)(sA + (mt * 16 + l15) * LDA + ks * 32 + quad * 8);
      for (int u = wid; u < 7; u += 4) {
        const int nt = u;
        const unsigned short* wb =
            ws + WO_OFF + lay * PL_QKVO + ((size_t)(nt * 4) * 64 + lane) * 8;
        const int n0 = nt * 16 + quad * 4;
        floatx4 bias = {0.f, 0.f, 0.f, 0.f};
        if (n0 < D) bias = *(const floatx4*)(bo + lay * D + n0);
        short8 wf[4];
#pragma unroll
        for (int ks = 0; ks < 4; ++ks) wf[ks] = *(const short8*)(wb + ks * 512);
        floatx4 a0 = bias, a1 = bias, a2 = bias;
#pragma unroll
        for (int ks = 0; ks < 4; ++ks) {
          a0 = __builtin_amdgcn_mfma_f32_16x16x32_bf16(wf[ks], cf[0][ks], a0, 0, 0, 0);
          a1 = __builtin_amdgcn_mfma_f32_16x16x32_bf16(wf[ks], cf[1][ks], a1, 0, 0, 0);
          a2 = __builtin_amdgcn_mfma_f32_16x16x32_bf16(wf[ks], cf[2][ks], a2, 0, 0, 0);
        }
        if (n0 < D) {
          const floatx4 av[3] = {a0, a1, a2};
#pragma unroll
          for (int mt = 0; mt < 3; ++mt) {
            const int row = mt * 16 + l15;
            const floatx4 res = *(const floatx4*)(sXf + row * 100 + n0);
            *(floatx4*)(sAcc + row * 100 + n0) = av[mt] + res;
          }
        }
      }
    }
    __syncthreads();
    ln_rows(sXf, sAcc, nullptr, g1 + lay * D, bt1 + lay * D, sA, tid);
    __syncthreads();

    // ---- FFN in 4 chunks of 128 hidden ----
    for (int c = 0; c < 4; ++c) {
      {  // FFN1: H = relu(X2 @ W1^T + b1) -> sH bf16
        short8 af[3][4];
#pragma unroll
        for (int mt = 0; mt < 3; ++mt)
#pragma unroll
          for (int ks = 0; ks < 4; ++ks)
            af[mt][ks] = *(const short8*)(sA + (mt * 16 + l15) * LDA + ks * 32 + quad * 8);
        for (int u = wid; u < 8; u += 4) {
          const int ntg = c * 8 + u;
          const unsigned short* wb =
              ws + W1_OFF + lay * PL_W1 + ((size_t)(ntg * 4) * 64 + lane) * 8;
          const int n0g = ntg * 16 + quad * 4;
          floatx4 bias = *(const floatx4*)(b1 + lay * FF + n0g);
          short8 wf[4];
#pragma unroll
          for (int ks = 0; ks < 4; ++ks) wf[ks] = *(const short8*)(wb + ks * 512);
          floatx4 a0 = bias, a1 = bias, a2 = bias;
#pragma unroll
          for (int ks = 0; ks < 4; ++ks) {
            a0 = __builtin_amdgcn_mfma_f32_16x16x32_bf16(wf[ks], af[0][ks], a0, 0, 0, 0);
            a1 = __builtin_amdgcn_mfma_f32_16x16x32_bf16(wf[ks], af[1][ks], a1, 0, 0, 0);
            a2 = __builtin_amdgcn_mfma_f32_16x16x32_bf16(wf[ks], af[2][ks], a2, 0, 0, 0);
          }
          const int n0l = u * 16 + quad * 4;
          const floatx4 av[3] = {a0, a1, a2};
#pragma unroll
          for (int mt = 0; mt < 3; ++mt) {
            const int row = mt * 16 + l15;
            const float r0 = fmaxf(av[mt].x, 0.f), r1 = fmaxf(av[mt].y, 0.f);
            const float r2 = fmaxf(av[mt].z, 0.f), r3 = fmaxf(av[mt].w, 0.f);
            unsigned int u0 = (unsigned)f2bf(r0) | ((unsigned)f2bf(r1) << 16);
            unsigned int u1 = (unsigned)f2bf(r2) | ((unsigned)f2bf(r3) << 16);
            *reinterpret_cast<uint2*>(sH + row * LDA + n0l) = make_uint2(u0, u1);
          }
        }
      }
      __syncthreads();
      {  // FFN2: sAcc (+)= H @ W2^T (+ b2 on chunk 0)
        short8 hf[3][4];
#pragma unroll
        for (int mt = 0; mt < 3; ++mt)
#pragma unroll
          for (int ks = 0; ks < 4; ++ks)
            hf[mt][ks] = *(const short8*)(sH + (mt * 16 + l15) * LDA + ks * 32 + quad * 8);
        for (int u = wid; u < 7; u += 4) {
          const int nt = u;
          const unsigned short* wb =
              ws + W2_OFF + lay * PL_W2 + ((size_t)(nt * 16 + c * 4) * 64 + lane) * 8;
          const int n0 = nt * 16 + quad * 4;
          floatx4 bias = {0.f, 0.f, 0.f, 0.f};
          if (c == 0 && n0 < D) bias = *(const floatx4*)(b2 + lay * D + n0);
          short8 wf[4];
#pragma unroll
          for (int ks = 0; ks < 4; ++ks) wf[ks] = *(const short8*)(wb + ks * 512);
          floatx4 a0 = bias, a1 = bias, a2 = bias;
#pragma unroll
          for (int ks = 0; ks < 4; ++ks) {
            a0 = __builtin_amdgcn_mfma_f32_16x16x32_bf16(wf[ks], hf[0][ks], a0, 0, 0, 0);
            a1 = __builtin_amdgcn_mfma_f32_16x16x32_bf16(wf[ks], hf[1][ks], a1, 0, 0, 0);
            a2 = __builtin_amdgcn_mfma_f32_16x16x32_bf16(wf[ks], hf[2][ks], a2, 0, 0, 0);
          }
          if (n0 < D) {
            const floatx4 av[3] = {a0, a1, a2};
#pragma unroll
            for (int mt = 0; mt < 3; ++mt) {
              const int row = mt * 16 + l15;
              if (c == 0) {
                *(floatx4*)(sAcc + row * 100 + n0) = av[mt];
              } else {
                const floatx4 p = *(const floatx4*)(sAcc + row * 100 + n0);
                *(floatx4*)(sAcc + row * 100 + n0) = p + av[mt];
              }
            }
          }
        }
      }
      __syncthreads();
    }
    ln_rows(sXf, sAcc, sXf, g2 + lay * D, bt2 + lay * D, sA, tid);
    __syncthreads();
  }

  // ---- classifier (VALU): out[e][c] = sXf[e][:300] . Wf[c] + bf[c] ----
  if (tid < 160) {
    const int c = tid % 40, eg = tid / 40;
    float acc[4];
#pragma unroll
    for (int i = 0; i < 4; ++i) acc[i] = bfc[c];
    const floatx4* wr = (const floatx4*)(Wf + c * 300);
    for (int kq = 0; kq < 75; ++kq) {
      const floatx4 w4 = wr[kq];
#pragma unroll
      for (int i = 0; i < 4; ++i) {
        const floatx4 x4 = *(const floatx4*)(sXf + (eg * 4 + i) * 300 + kq * 4);
        acc[i] += w4.x * x4.x + w4.y * x4.y + w4.z * x4.z + w4.w * x4.w;
      }
    }
#pragma unroll
    for (int i = 0; i < 4; ++i)
      gout[((size_t)blk * NB + eg * 4 + i) * CLS + c] = acc[i];
  }
}

extern "C" void kernel_launch(void* const* d_in, const int* in_sizes, int n_in,
                              void* d_out, int out_size, void* d_ws,
                              size_t ws_size, hipStream_t stream) {
  const float* x   = (const float*)d_in[0];
  const float* We  = (const float*)d_in[3];
  const float* be  = (const float*)d_in[4];
  const float* pe  = (const float*)d_in[5];
  const float* Wq  = (const float*)d_in[6];
  const float* bq  = (const float*)d_in[7];
  const float* Wk  = (const float*)d_in[8];
  const float* bk  = (const float*)d_in[9];
  const float* Wv  = (const float*)d_in[10];
  const float* bv  = (const float*)d_in[11];
  const float* Wo  = (const float*)d_in[12];
  const float* bo  = (const float*)d_in[13];
  const float* g1  = (const float*)d_in[14];
  const float* bt1 = (const float*)d_in[15];
  const float* W1  = (const float*)d_in[16];
  const float* b1  = (const float*)d_in[17];
  const float* W2  = (const float*)d_in[18];
  const float* b2  = (const float*)d_in[19];
  const float* g2  = (const float*)d_in[20];
  const float* bt2 = (const float*)d_in[21];
  const float* Wf  = (const float*)d_in[22];
  const float* bf  = (const float*)d_in[23];
  float* out = (float*)d_out;
  unsigned short* ws = (unsigned short*)d_ws;

  // pre-pack weights -> bf16 fragment blocks (180224 threads)
  prep_weights<<<704, 256, 0, stream>>>(Wq, Wk, Wv, Wo, W1, W2, ws);

  const int B = in_sizes[0] / (S * DIN);
  const int blocks = B / NB;  // 4096
  geomap_mfma<<<blocks, 256, 0, stream>>>(x, We, be, pe, bq, bk, bv, bo,
                                          g1, bt1, b1, b2, g2, bt2, Wf, bf,
                                          ws, out);
}

// Round 4
// 1474.048 us; speedup vs baseline: 11.1426x; 1.2338x over previous
//
#include <hip/hip_runtime.h>
#include <hip/hip_bf16.h>

// GeoMapNet fused forward, MFMA bf16, register-resident fp32 master.
// Block = 256 threads (4 waves) = NB(16) elements = 48 (e,s) rows.
// LDS 41856 B -> 3 blocks/CU. fp32 master activations live in the registers
// of 192 "owner" threads (4 lanes per row, 25 floats each); pre-LN sums pass
// through a fp32 scratch that time-aliases the dead Q/K/V | FFN-hidden region.
// All GEMMs (incl. embedding) use v_mfma_f32_16x16x32_bf16, W as A-operand.
// Weight fragments pre-packed to bf16 by prep_weights into d_ws.
// R4 fix: V-plane row stride 98 -> 100 (rows hold 100 bf16; 98 clobbered the
// next row at n0=96 and misaligned every subsequent row).

typedef __attribute__((ext_vector_type(8))) short short8;   // 8 bf16
typedef __attribute__((ext_vector_type(4))) float floatx4;  // MFMA C/D

namespace {
constexpr int S = 3, DIN = 72, D = 100, FF = 512, L = 8, CLS = 40;
constexpr int NB = 16, R = 48, NT = 256;
constexpr int LDA = 136;   // sA row stride (shorts): 16B-aligned
constexpr int LDH = 264;   // sH row stride (shorts)
constexpr int LDV = 100;   // sV row stride (shorts) == row payload
constexpr float SCALE = 0.3162277660168379f;  // DH^-0.5

// d_ws element offsets (bf16). Fragment block = 64 lanes x 8 bf16.
constexpr int PL_QKVO = 7 * 4 * 512;                 // per layer
constexpr int WQ_OFF = 0;
constexpr int WK_OFF = WQ_OFF + L * PL_QKVO;
constexpr int WV_OFF = WK_OFF + L * PL_QKVO;
constexpr int WO_OFF = WV_OFF + L * PL_QKVO;
constexpr int PL_W1 = 32 * 4 * 512;
constexpr int W1_OFF = WO_OFF + L * PL_QKVO;
constexpr int PL_W2 = 7 * 16 * 512;
constexpr int W2_OFF = W1_OFF + L * PL_W1;
constexpr int WE_OFF = W2_OFF + L * PL_W2;           // 7 nt x 3 ks
// total = WE_OFF + 7*3*512 = 1,452,544 elems = 2,905,088 bytes
}  // namespace

__device__ __forceinline__ unsigned short f2bf(float f) {  // RTNE (prep only)
  unsigned int u = __float_as_uint(f);
  u = u + 0x7fffu + ((u >> 16) & 1u);
  return (unsigned short)(u >> 16);
}

__device__ __forceinline__ unsigned pkbf(float a, float b) {  // packed cvt
  __hip_bfloat162 h = __float22bfloat162_rn(make_float2(a, b));
  return *reinterpret_cast<unsigned*>(&h);
}

__device__ __forceinline__ void st_bf4(unsigned short* p, floatx4 v) {
  *reinterpret_cast<uint2*>(p) = make_uint2(pkbf(v.x, v.y), pkbf(v.z, v.w));
}

__device__ __forceinline__ void load10(float* o, const unsigned short* p) {
  const unsigned* u = (const unsigned*)p;  // 4B-aligned (even col)
#pragma unroll
  for (int w = 0; w < 5; ++w) {
    unsigned x = u[w];
    o[2 * w] = __uint_as_float(x << 16);
    o[2 * w + 1] = __uint_as_float(x & 0xffff0000u);
  }
}

__device__ __forceinline__ void ldwf4(const unsigned short* base, short8* o) {
#pragma unroll
  for (int ks = 0; ks < 4; ++ks) o[ks] = *(const short8*)(base + ks * 512);
}

// Owner LayerNorm: t = M + scr_row; M = LN(t)*g+b; write bf16 to sA row.
__device__ __forceinline__ void owner_ln(floatx4* M, const float* scrRow,
                                         const float* __restrict__ g,
                                         const float* __restrict__ b,
                                         unsigned short* sARow, int ln_o,
                                         int cnt) {
  floatx4 v[7];
  float sum = 0.f;
#pragma unroll
  for (int i = 0; i < 7; ++i)
    if (i < cnt) {
      const int col = i * 16 + ln_o * 4;
      floatx4 t = M[i] + *(const floatx4*)(scrRow + col);
      v[i] = t;
      sum += t.x + t.y + t.z + t.w;
    }
  sum += __shfl_xor(sum, 1, 4);
  sum += __shfl_xor(sum, 2, 4);
  const float mean = sum * 0.01f;
  float var = 0.f;
#pragma unroll
  for (int i = 0; i < 7; ++i)
    if (i < cnt) {
      floatx4 d = v[i] - mean;
      var += d.x * d.x + d.y * d.y + d.z * d.z + d.w * d.w;
    }
  var += __shfl_xor(var, 1, 4);
  var += __shfl_xor(var, 2, 4);
  const float rstd = rsqrtf(var * 0.01f + 1e-5f);
#pragma unroll
  for (int i = 0; i < 7; ++i)
    if (i < cnt) {
      const int col = i * 16 + ln_o * 4;
      floatx4 o = (v[i] - mean) * rstd * *(const floatx4*)(g + col) +
                  *(const floatx4*)(b + col);
      M[i] = o;
      st_bf4(sARow + col, o);
    }
}

// ------------- weight pre-pack: fp32 row-major -> bf16 fragment blocks -----
__global__ void prep_weights(const float* __restrict__ Wq, const float* __restrict__ Wk,
                             const float* __restrict__ Wv, const float* __restrict__ Wo,
                             const float* __restrict__ W1, const float* __restrict__ W2,
                             const float* __restrict__ We,
                             unsigned short* __restrict__ ws) {
  const int gid = blockIdx.x * 256 + threadIdx.x;
  constexpr int T_QKVO = 8 * 7 * 4 * 64;  // 14336
  constexpr int T_W1 = 8 * 32 * 4 * 64;   // 65536
  constexpr int T_W2 = 8 * 7 * 16 * 64;   // 57344
  constexpr int T_WE = 7 * 3 * 64;        // 1344
  if (gid >= 4 * T_QKVO + T_W1 + T_W2 + T_WE) return;

  const float* src;
  unsigned short* dst;
  int within, ntc, ksc, N, Ksrc, lstride;
  if (gid < 4 * T_QKVO) {
    const int t = gid / T_QKVO;
    within = gid % T_QKVO;
    src = (t == 0 ? Wq : t == 1 ? Wk : t == 2 ? Wv : Wo);
    dst = ws + (t == 0 ? WQ_OFF : t == 1 ? WK_OFF : t == 2 ? WV_OFF : WO_OFF);
    ntc = 7; ksc = 4; N = 100; Ksrc = 100; lstride = 10000;
  } else if (gid < 4 * T_QKVO + T_W1) {
    within = gid - 4 * T_QKVO;
    src = W1; dst = ws + W1_OFF;
    ntc = 32; ksc = 4; N = 512; Ksrc = 100; lstride = 51200;
  } else if (gid < 4 * T_QKVO + T_W1 + T_W2) {
    within = gid - 4 * T_QKVO - T_W1;
    src = W2; dst = ws + W2_OFF;
    ntc = 7; ksc = 16; N = 100; Ksrc = 512; lstride = 51200;
  } else {
    within = gid - 4 * T_QKVO - T_W1 - T_W2;
    src = We; dst = ws + WE_OFF;
    ntc = 7; ksc = 3; N = 100; Ksrc = 72; lstride = 0;
  }
  const int lane = within & 63;
  int tmp = within >> 6;
  const int ks = tmp % ksc; tmp /= ksc;
  const int nt = tmp % ntc;
  const int lay = tmp / ntc;
  const int n = nt * 16 + (lane & 15);
  const int kb = ks * 32 + (lane >> 4) * 8;
  const float* sp = src + (size_t)lay * lstride + (size_t)n * Ksrc;
  unsigned short o[8];
#pragma unroll
  for (int j = 0; j < 8; ++j) {
    const int k = kb + j;
    float v = (n < N && k < Ksrc) ? sp[k] : 0.f;
    o[j] = f2bf(v);
  }
  uint4 pk = make_uint4((unsigned)o[0] | ((unsigned)o[1] << 16),
                        (unsigned)o[2] | ((unsigned)o[3] << 16),
                        (unsigned)o[4] | ((unsigned)o[5] << 16),
                        (unsigned)o[6] | ((unsigned)o[7] << 16));
  *reinterpret_cast<uint4*>(dst + (size_t)within * 8) = pk;
}

__global__ __launch_bounds__(NT, 3)
void geomap_mfma(const float* __restrict__ gx,
                 const float* __restrict__ be, const float* __restrict__ pe,
                 const float* __restrict__ bq, const float* __restrict__ bk,
                 const float* __restrict__ bv, const float* __restrict__ bo,
                 const float* __restrict__ g1, const float* __restrict__ bt1,
                 const float* __restrict__ b1, const float* __restrict__ b2,
                 const float* __restrict__ g2, const float* __restrict__ bt2,
                 const float* __restrict__ Wf, const float* __restrict__ bfc,
                 const unsigned short* __restrict__ ws,
                 float* __restrict__ gout) {
  __shared__ __align__(16) char smem[41856];
  unsigned short* sA = (unsigned short*)smem;            // [48][136] bf16 X
  unsigned short* sQ = (unsigned short*)(smem + 13056);  // [48][100] bf16
  unsigned short* sK = (unsigned short*)(smem + 22656);  // [48][100]
  unsigned short* sV = (unsigned short*)(smem + 32256);  // [48][100]
  unsigned short* sH = (unsigned short*)(smem + 13056);  // [48][264] (alias)
  float* scr = (float*)(smem + 13056);                   // [48][100] (alias)

  const int tid = threadIdx.x;
  const int lane = tid & 63;
  const int wid = tid >> 6;
  const int l15 = lane & 15;
  const int quad = lane >> 4;
  const int blk = blockIdx.x;

  const bool owner = tid < 192;
  const int row_o = tid >> 2, ln_o = tid & 3;
  const int cnt_o = (ln_o == 0) ? 7 : 6;
  floatx4 M[7];  // fp32 master: 25 values per owner thread

  // ---- zero sA (pad cols stay 0 forever), then stage x as bf16 ----
  for (int i = tid; i < R * LDA / 2; i += NT) ((unsigned*)sA)[i] = 0u;
  __syncthreads();
  for (int i = tid; i < R * DIN / 2; i += NT) {
    const int row = i / 36, c = (i % 36) * 2;
    const float2 f2 = *(const float2*)(gx + ((size_t)blk * R + row) * DIN + c);
    ((unsigned*)sA)[row * (LDA / 2) + (c >> 1)] = pkbf(f2.x, f2.y);
  }
  __syncthreads();

  // ---- embedding via MFMA: X = x @ We^T + be + pe ----
  {
    short8 xe[3][3];
#pragma unroll
    for (int mt = 0; mt < 3; ++mt)
#pragma unroll
      for (int ks = 0; ks < 3; ++ks)
        xe[mt][ks] = *(const short8*)(sA + (mt * 16 + l15) * LDA + ks * 32 + quad * 8);
    __syncthreads();  // all x-frags in regs before epilogue overwrites sA
    for (int nt = wid; nt < 7; nt += 4) {
      const unsigned short* wb = ws + WE_OFF + (size_t)(nt * 3) * 512 + (size_t)lane * 8;
      short8 w0 = *(const short8*)(wb);
      short8 w1 = *(const short8*)(wb + 512);
      short8 w2 = *(const short8*)(wb + 1024);
      const int n0 = nt * 16 + quad * 4;
      floatx4 a[3];
#pragma unroll
      for (int mt = 0; mt < 3; ++mt) {
        a[mt] = floatx4{0.f, 0.f, 0.f, 0.f};
        a[mt] = __builtin_amdgcn_mfma_f32_16x16x32_bf16(w0, xe[mt][0], a[mt], 0, 0, 0);
        a[mt] = __builtin_amdgcn_mfma_f32_16x16x32_bf16(w1, xe[mt][1], a[mt], 0, 0, 0);
        a[mt] = __builtin_amdgcn_mfma_f32_16x16x32_bf16(w2, xe[mt][2], a[mt], 0, 0, 0);
      }
      if (n0 < D) {
        const floatx4 bev = *(const floatx4*)(be + n0);
#pragma unroll
        for (int mt = 0; mt < 3; ++mt) {
          const int row = mt * 16 + l15;
          const int s = row % 3;
          const floatx4 pev = *(const floatx4*)(pe + s * D + n0);
          const floatx4 o = a[mt] + bev + pev;
          *(floatx4*)(scr + row * D + n0) = o;
          st_bf4(sA + row * LDA + n0, o);
        }
      }
    }
  }
  __syncthreads();
  if (owner) {
#pragma unroll
    for (int i = 0; i < 7; ++i)
      if (i < cnt_o) M[i] = *(const floatx4*)(scr + row_o * D + i * 16 + ln_o * 4);
  }
  __syncthreads();  // scratch free before QKV epilogue writes

  for (int lay = 0; lay < L; ++lay) {
    // ---- QKV: 21 units, rolling wf prefetch ----
    {
      short8 xf[3][4];
#pragma unroll
      for (int mt = 0; mt < 3; ++mt)
#pragma unroll
        for (int ks = 0; ks < 4; ++ks)
          xf[mt][ks] = *(const short8*)(sA + (mt * 16 + l15) * LDA + ks * 32 + quad * 8);
      const unsigned short* wbase[3] = {ws + WQ_OFF + lay * PL_QKVO,
                                        ws + WK_OFF + lay * PL_QKVO,
                                        ws + WV_OFF + lay * PL_QKVO};
      short8 wf[4];
      ldwf4(wbase[wid / 7] + (size_t)(wid % 7) * 2048 + (size_t)lane * 8, wf);
      for (int u = wid; u < 21; u += 4) {
        short8 nwf[4];
        const bool more = (u + 4 < 21);
        if (more)
          ldwf4(wbase[(u + 4) / 7] + (size_t)((u + 4) % 7) * 2048 + (size_t)lane * 8, nwf);
        const int mat = u / 7, nt = u % 7;
        const int n0 = nt * 16 + quad * 4;
        floatx4 bias = {0.f, 0.f, 0.f, 0.f};
        const float* bsrc = (mat == 0 ? bq : mat == 1 ? bk : bv) + lay * D;
        if (n0 < D) bias = *(const floatx4*)(bsrc + n0);
        floatx4 a0 = bias, a1 = bias, a2 = bias;
#pragma unroll
        for (int ks = 0; ks < 4; ++ks) {
          a0 = __builtin_amdgcn_mfma_f32_16x16x32_bf16(wf[ks], xf[0][ks], a0, 0, 0, 0);
          a1 = __builtin_amdgcn_mfma_f32_16x16x32_bf16(wf[ks], xf[1][ks], a1, 0, 0, 0);
          a2 = __builtin_amdgcn_mfma_f32_16x16x32_bf16(wf[ks], xf[2][ks], a2, 0, 0, 0);
        }
        if (n0 < D) {
          const floatx4 av[3] = {a0, a1, a2};
#pragma unroll
          for (int mt = 0; mt < 3; ++mt) {
            const int row = mt * 16 + l15;
            if (mat == 0) st_bf4(sQ + row * 100 + n0, av[mt]);
            else if (mat == 1) st_bf4(sK + row * 100 + n0, av[mt]);
            else {  // V: dword stores (odd rows not 8B-aligned at stride 100)
              unsigned* dp = (unsigned*)(sV + row * LDV + n0);
              dp[0] = pkbf(av[mt].x, av[mt].y);
              dp[1] = pkbf(av[mt].z, av[mt].w);
            }
          }
        }
#pragma unroll
        for (int ks = 0; ks < 4; ++ks) wf[ks] = more ? nwf[ks] : wf[ks];
      }
    }
    __syncthreads();

    // ---- attention: 160 jobs = (e, h), faithful .view head split ----
    if (tid < 160) {
      const int e = tid / 10, h = tid % 10;
      const unsigned short* Qe = sQ + e * 300;  // stride 100 -> flat 300
      const unsigned short* Ke = sK + e * 300;
      const unsigned short* Ve = sV + e * 300;
      float K[3][10], V[3][10];
#pragma unroll
      for (int t = 0; t < 3; ++t) {
        load10(K[t], Ke + h * 30 + t * 10);
        load10(V[t], Ve + h * 30 + t * 10);
      }
#pragma unroll
      for (int sq = 0; sq < 3; ++sq) {
        float q[10];
        load10(q, Qe + h * 30 + sq * 10);
        float sc[3];
#pragma unroll
        for (int t = 0; t < 3; ++t) {
          float s0 = 0.f;
#pragma unroll
          for (int j = 0; j < 10; ++j) s0 += q[j] * K[t][j];
          sc[t] = s0 * SCALE;
        }
        const float m = fmaxf(sc[0], fmaxf(sc[1], sc[2]));
        float p0 = __expf(sc[0] - m), p1 = __expf(sc[1] - m), p2 = __expf(sc[2] - m);
        const float inv = 1.f / (p0 + p1 + p2);
        p0 *= inv; p1 *= inv; p2 *= inv;
        float ctx[10];
#pragma unroll
        for (int j = 0; j < 10; ++j)
          ctx[j] = p0 * V[0][j] + p1 * V[1][j] + p2 * V[2][j];
        const int p = h * 30 + sq * 10;
        unsigned* dp = (unsigned*)(sA + (e * 3 + p / 100) * LDA + (p % 100));
#pragma unroll
        for (int w = 0; w < 5; ++w) dp[w] = pkbf(ctx[2 * w], ctx[2 * w + 1]);
      }
    }
    __syncthreads();

    // ---- Wo -> scratch (no residual; owners add M at LN1) ----
    {
      short8 cf[3][4];
#pragma unroll
      for (int mt = 0; mt < 3; ++mt)
#pragma unroll
        for (int ks = 0; ks < 4; ++ks)
          cf[mt][ks] = *(const short8*)(sA + (mt * 16 + l15) * LDA + ks * 32 + quad * 8);
      const unsigned short* wbase = ws + WO_OFF + lay * PL_QKVO;
      short8 wf[4];
      ldwf4(wbase + (size_t)wid * 2048 + (size_t)lane * 8, wf);
      for (int u = wid; u < 7; u += 4) {
        short8 nwf[4];
        const bool more = (u + 4 < 7);
        if (more) ldwf4(wbase + (size_t)(u + 4) * 2048 + (size_t)lane * 8, nwf);
        const int n0 = u * 16 + quad * 4;
        floatx4 bias = {0.f, 0.f, 0.f, 0.f};
        if (n0 < D) bias = *(const floatx4*)(bo + lay * D + n0);
        floatx4 a0 = bias, a1 = bias, a2 = bias;
#pragma unroll
        for (int ks = 0; ks < 4; ++ks) {
          a0 = __builtin_amdgcn_mfma_f32_16x16x32_bf16(wf[ks], cf[0][ks], a0, 0, 0, 0);
          a1 = __builtin_amdgcn_mfma_f32_16x16x32_bf16(wf[ks], cf[1][ks], a1, 0, 0, 0);
          a2 = __builtin_amdgcn_mfma_f32_16x16x32_bf16(wf[ks], cf[2][ks], a2, 0, 0, 0);
        }
        if (n0 < D) {
          const floatx4 av[3] = {a0, a1, a2};
#pragma unroll
          for (int mt = 0; mt < 3; ++mt)
            *(floatx4*)(scr + (mt * 16 + l15) * D + n0) = av[mt];
        }
#pragma unroll
        for (int ks = 0; ks < 4; ++ks) wf[ks] = more ? nwf[ks] : wf[ks];
      }
    }
    __syncthreads();
    if (owner)
      owner_ln(M, scr + row_o * D, g1 + lay * D, bt1 + lay * D,
               sA + row_o * LDA, ln_o, cnt_o);
    __syncthreads();

    // ---- FFN: 2 chunks of 256 hidden; FFN2 acc persistent in VGPRs ----
    {
      short8 ff[3][4];
#pragma unroll
      for (int mt = 0; mt < 3; ++mt)
#pragma unroll
        for (int ks = 0; ks < 4; ++ks)
          ff[mt][ks] = *(const short8*)(sA + (mt * 16 + l15) * LDA + ks * 32 + quad * 8);
      floatx4 facc[2][3];
#pragma unroll
      for (int idx = 0; idx < 2; ++idx) {
        const int nt = wid + 4 * idx;
        const int n0 = nt * 16 + quad * 4;
        floatx4 bias = {0.f, 0.f, 0.f, 0.f};
        if (nt < 7 && n0 < D) bias = *(const floatx4*)(b2 + lay * D + n0);
#pragma unroll
        for (int mt = 0; mt < 3; ++mt) facc[idx][mt] = bias;
      }
      const unsigned short* w1b = ws + W1_OFF + (size_t)lay * PL_W1;
      const unsigned short* w2b = ws + W2_OFF + (size_t)lay * PL_W2;
      const int nts1 = wid + 4;  // second FFN2 nt (valid if < 7)

      for (int c = 0; c < 2; ++c) {
        // FFN1: 4 units per wave, rolling prefetch
        short8 wf[4];
        ldwf4(w1b + (size_t)(c * 16 + wid) * 2048 + (size_t)lane * 8, wf);
#pragma unroll
        for (int k = 0; k < 4; ++k) {
          const int ntg = c * 16 + wid + 4 * k;
          short8 nwf[4];
          if (k < 3)
            ldwf4(w1b + (size_t)(ntg + 4) * 2048 + (size_t)lane * 8, nwf);
          const floatx4 b1v = *(const floatx4*)(b1 + lay * FF + ntg * 16 + quad * 4);
          floatx4 a0 = b1v, a1 = b1v, a2 = b1v;
#pragma unroll
          for (int ks = 0; ks < 4; ++ks) {
            a0 = __builtin_amdgcn_mfma_f32_16x16x32_bf16(wf[ks], ff[0][ks], a0, 0, 0, 0);
            a1 = __builtin_amdgcn_mfma_f32_16x16x32_bf16(wf[ks], ff[1][ks], a1, 0, 0, 0);
            a2 = __builtin_amdgcn_mfma_f32_16x16x32_bf16(wf[ks], ff[2][ks], a2, 0, 0, 0);
          }
          const int nloc = (wid + 4 * k) * 16 + quad * 4;
          const floatx4 av[3] = {a0, a1, a2};
#pragma unroll
          for (int mt = 0; mt < 3; ++mt) {
            const int row = mt * 16 + l15;
            floatx4 r;
            r.x = fmaxf(av[mt].x, 0.f); r.y = fmaxf(av[mt].y, 0.f);
            r.z = fmaxf(av[mt].z, 0.f); r.w = fmaxf(av[mt].w, 0.f);
            st_bf4(sH + row * LDH + nloc, r);
          }
          if (k < 3) {
#pragma unroll
            for (int ks = 0; ks < 4; ++ks) wf[ks] = nwf[ks];
          }
        }
        __syncthreads();
        // FFN2: shared hf across the wave's 1-2 nt units, wf pair prefetch
        short8 wA = *(const short8*)(w2b + (size_t)(wid * 16 + c * 8) * 512 + (size_t)lane * 8);
        short8 wB = wA;
        if (nts1 < 7)
          wB = *(const short8*)(w2b + (size_t)(nts1 * 16 + c * 8) * 512 + (size_t)lane * 8);
#pragma unroll
        for (int ksl = 0; ksl < 8; ++ksl) {
          short8 nA = wA, nB = wB;
          if (ksl < 7) {
            nA = *(const short8*)(w2b + (size_t)(wid * 16 + c * 8 + ksl + 1) * 512 + (size_t)lane * 8);
            if (nts1 < 7)
              nB = *(const short8*)(w2b + (size_t)(nts1 * 16 + c * 8 + ksl + 1) * 512 + (size_t)lane * 8);
          }
          short8 hf[3];
#pragma unroll
          for (int mt = 0; mt < 3; ++mt)
            hf[mt] = *(const short8*)(sH + (mt * 16 + l15) * LDH + ksl * 32 + quad * 8);
#pragma unroll
          for (int mt = 0; mt < 3; ++mt)
            facc[0][mt] = __builtin_amdgcn_mfma_f32_16x16x32_bf16(wA, hf[mt], facc[0][mt], 0, 0, 0);
          if (nts1 < 7) {
#pragma unroll
            for (int mt = 0; mt < 3; ++mt)
              facc[1][mt] = __builtin_amdgcn_mfma_f32_16x16x32_bf16(wB, hf[mt], facc[1][mt], 0, 0, 0);
          }
          wA = nA; wB = nB;
        }
        __syncthreads();  // sH consumed (next FFN1 write / scratch write safe)
      }
      // FFN2 epilogue -> scratch
#pragma unroll
      for (int idx = 0; idx < 2; ++idx) {
        const int nt = wid + 4 * idx;
        const int n0 = nt * 16 + quad * 4;
        if (nt < 7 && n0 < D) {
#pragma unroll
          for (int mt = 0; mt < 3; ++mt)
            *(floatx4*)(scr + (mt * 16 + l15) * D + n0) = facc[idx][mt];
        }
      }
    }
    __syncthreads();
    if (owner)
      owner_ln(M, scr + row_o * D, g2 + lay * D, bt2 + lay * D,
               sA + row_o * LDA, ln_o, cnt_o);
    __syncthreads();
  }

  // ---- dump master -> scratch, then classifier (fp32 VALU, exact) ----
  if (owner) {
#pragma unroll
    for (int i = 0; i < 7; ++i)
      if (i < cnt_o)
        *(floatx4*)(scr + row_o * D + i * 16 + ln_o * 4) = M[i];
  }
  __syncthreads();
  if (tid < 160) {
    const int c = tid % 40, eg = tid / 40;
    float acc[4];
#pragma unroll
    for (int i = 0; i < 4; ++i) acc[i] = bfc[c];
    const floatx4* wr = (const floatx4*)(Wf + c * 300);
    for (int kq = 0; kq < 75; ++kq) {
      const floatx4 w4 = wr[kq];
#pragma unroll
      for (int i = 0; i < 4; ++i) {
        const floatx4 x4 = *(const floatx4*)(scr + (eg * 4 + i) * 300 + kq * 4);
        acc[i] += w4.x * x4.x + w4.y * x4.y + w4.z * x4.z + w4.w * x4.w;
      }
    }
#pragma unroll
    for (int i = 0; i < 4; ++i)
      gout[((size_t)blk * NB + eg * 4 + i) * CLS + c] = acc[i];
  }
}

extern "C" void kernel_launch(void* const* d_in, const int* in_sizes, int n_in,
                              void* d_out, int out_size, void* d_ws,
                              size_t ws_size, hipStream_t stream) {
  const float* x   = (const float*)d_in[0];
  const float* We  = (const float*)d_in[3];
  const float* be  = (const float*)d_in[4];
  const float* pe  = (const float*)d_in[5];
  const float* Wq  = (const float*)d_in[6];
  const float* bq  = (const float*)d_in[7];
  const float* Wk  = (const float*)d_in[8];
  const float* bk  = (const float*)d_in[9];
  const float* Wv  = (const float*)d_in[10];
  const float* bv  = (const float*)d_in[11];
  const float* Wo  = (const float*)d_in[12];
  const float* bo  = (const float*)d_in[13];
  const float* g1  = (const float*)d_in[14];
  const float* bt1 = (const float*)d_in[15];
  const float* W1  = (const float*)d_in[16];
  const float* b1  = (const float*)d_in[17];
  const float* W2  = (const float*)d_in[18];
  const float* b2  = (const float*)d_in[19];
  const float* g2  = (const float*)d_in[20];
  const float* bt2 = (const float*)d_in[21];
  const float* Wf  = (const float*)d_in[22];
  const float* bf  = (const float*)d_in[23];
  float* out = (float*)d_out;
  unsigned short* ws = (unsigned short*)d_ws;

  prep_weights<<<710, 256, 0, stream>>>(Wq, Wk, Wv, Wo, W1, W2, We, ws);

  const int B = in_sizes[0] / (S * DIN);
  const int blocks = B / NB;  // 4096
  geomap_mfma<<<blocks, 256, 0, stream>>>(x, be, pe, bq, bk, bv, bo,
                                          g1, bt1, b1, b2, g2, bt2, Wf, bf,
                                          ws, out);
}